// Round 1
// baseline (1206.302 us; speedup 1.0000x reference)
//
#include <hip/hip_runtime.h>
#include <math.h>

#define NTOT   262144
#define ROWS   64
#define PITCH  65
#define THREADS 256

__global__ __launch_bounds__(THREADS, 2)
void gmm_fused(const float* __restrict__ cond,
               const float* __restrict__ rnd,
               const float* __restrict__ W0, const float* __restrict__ b0,
               const float* __restrict__ W1, const float* __restrict__ b1,
               const float* __restrict__ W2, const float* __restrict__ b2,
               const float* __restrict__ W3, const float* __restrict__ b3,
               const float* __restrict__ W4, const float* __restrict__ b4,
               float* __restrict__ out)
{
    extern __shared__ float smem[];
    float* Bs0 = smem;                 // [128][PITCH]
    float* Bs1 = smem + 128 * PITCH;   // [128][PITCH]

    const int tid  = threadIdx.x;
    const int lane = tid & 63;
    const int wv   = tid >> 6;
    const int row0 = blockIdx.x * ROWS;

    // ---- stage cond^T into Bs0[c][r] (float4 coalesced) ----
    {
        const float4* cond4 = (const float4*)cond;
        for (int i = tid; i < 64 * 16; i += THREADS) {
            int r = i >> 4, c4 = i & 15;
            float4 v = cond4[(size_t)(row0 + r) * 16 + c4];
            Bs0[(4 * c4 + 0) * PITCH + r] = v.x;
            Bs0[(4 * c4 + 1) * PITCH + r] = v.y;
            Bs0[(4 * c4 + 2) * PITCH + r] = v.z;
            Bs0[(4 * c4 + 3) * PITCH + r] = v.w;
        }
    }
    __syncthreads();

    const int wc32 = __builtin_amdgcn_readfirstlane(wv * 32);

    // ---- L0: 64 -> 128 (relu): Bs0 -> Bs1 ----
    {
        float acc[32];
        #pragma unroll
        for (int c = 0; c < 32; ++c) acc[c] = b0[wc32 + c];
        #pragma unroll 4
        for (int k = 0; k < 64; ++k) {
            float a = Bs0[k * PITCH + lane];
            const float* wr = W0 + k * 128 + wc32;
            #pragma unroll
            for (int c = 0; c < 32; ++c) acc[c] = fmaf(a, wr[c], acc[c]);
        }
        #pragma unroll
        for (int c = 0; c < 32; ++c)
            Bs1[(wc32 + c) * PITCH + lane] = fmaxf(acc[c], 0.0f);
    }
    __syncthreads();

    // ---- L1 (128->512, relu) + L2 (512->128) fused over 4 chunks of 128 ----
    float acc2[32];
    #pragma unroll
    for (int c = 0; c < 32; ++c) acc2[c] = b2[wc32 + c];

    for (int chunk = 0; chunk < 4; ++chunk) {
        float t[32];
        const int cb = chunk * 128 + wc32;
        #pragma unroll
        for (int c = 0; c < 32; ++c) t[c] = b1[cb + c];
        #pragma unroll 2
        for (int k = 0; k < 128; ++k) {
            float a = Bs1[k * PITCH + lane];
            const float* wr = W1 + (size_t)k * 512 + cb;
            #pragma unroll
            for (int c = 0; c < 32; ++c) t[c] = fmaf(a, wr[c], t[c]);
        }
        __syncthreads();   // all waves done reading Bs0 from previous chunk
        #pragma unroll
        for (int c = 0; c < 32; ++c)
            Bs0[(wc32 + c) * PITCH + lane] = fmaxf(t[c], 0.0f);
        __syncthreads();   // chunk activations visible
        #pragma unroll 2
        for (int k = 0; k < 128; ++k) {
            float a = Bs0[k * PITCH + lane];
            const float* wr = W2 + (size_t)(chunk * 128 + k) * 128 + wc32;
            #pragma unroll
            for (int c = 0; c < 32; ++c) acc2[c] = fmaf(a, wr[c], acc2[c]);
        }
    }
    __syncthreads();       // all L2 reads + all Bs1(h1) reads complete
    #pragma unroll
    for (int c = 0; c < 32; ++c)
        Bs1[(wc32 + c) * PITCH + lane] = fmaxf(acc2[c], 0.0f);
    __syncthreads();

    // ---- L3: 128 -> 32 (relu): Bs1 -> Bs0 ----
    const int wc8 = __builtin_amdgcn_readfirstlane(wv * 8);
    {
        float acc[8];
        #pragma unroll
        for (int c = 0; c < 8; ++c) acc[c] = b3[wc8 + c];
        #pragma unroll 4
        for (int k = 0; k < 128; ++k) {
            float a = Bs1[k * PITCH + lane];
            const float* wr = W3 + k * 32 + wc8;
            #pragma unroll
            for (int c = 0; c < 8; ++c) acc[c] = fmaf(a, wr[c], acc[c]);
        }
        #pragma unroll
        for (int c = 0; c < 8; ++c)
            Bs0[(wc8 + c) * PITCH + lane] = fmaxf(acc[c], 0.0f);
    }
    __syncthreads();

    // ---- L4: 32 -> 41 (no relu): Bs0 -> Bs1 ----
    const int wc12 = __builtin_amdgcn_readfirstlane(wv * 12);
    {
        float acc[12];
        #pragma unroll
        for (int c = 0; c < 12; ++c) acc[c] = (wc12 + c < 41) ? b4[wc12 + c] : 0.0f;
        #pragma unroll 4
        for (int k = 0; k < 32; ++k) {
            float a = Bs0[k * PITCH + lane];
            const float* wr = W4 + k * 41;
            #pragma unroll
            for (int c = 0; c < 12; ++c)
                if (wc12 + c < 41) acc[c] = fmaf(a, wr[wc12 + c], acc[c]);
        }
        #pragma unroll
        for (int c = 0; c < 12; ++c)
            if (wc12 + c < 41) Bs1[(wc12 + c) * PITCH + lane] = acc[c];
    }
    __syncthreads();

    // ---- epilogue: wave 0, one lane per row ----
    if (wv == 0) {
        const int row = row0 + lane;
        float h[41];
        #pragma unroll
        for (int j = 0; j < 41; ++j) h[j] = Bs1[j * PITCH + lane];

        float2 rv = ((const float2*)rnd)[row];
        float r0v = rv.x, r1v = rv.y;

        float wraw[9];
        float wsum = 0.0f;
        #pragma unroll
        for (int j = 0; j < 9; ++j) { wraw[j] = fabsf(h[32 + j]); wsum += wraw[j]; }
        float wL = wraw[8] / wsum;

        const bool lambert = r0v < wL;
        float u0 = lambert ? (r0v / wL) : ((r0v - wL) / (1.0f - wL));
        float U1 = lambert ? 0.5f : u0;
        U1 = fmaxf(U1, 1e-12f);
        float R  = sqrtf(-2.0f * logf(U1));
        float th = 6.28318530717958647692f * r1v;
        float ce = cosf(th), se = sinf(th);

        float es0[8], es1[8];
        float ssum0 = 0.0f, ssum1 = 0.0f, lsum0 = 0.0f, lsum1 = 0.0f;
        #pragma unroll
        for (int m = 0; m < 8; ++m) {
            es0[m] = expf(h[16 + 2 * m]);
            es1[m] = expf(h[16 + 2 * m + 1]);
            ssum0 += es0[m]; ssum1 += es1[m];
            lsum0 += h[2 * m]; lsum1 += h[2 * m + 1];
        }
        float zg0 = (R * ce) * ssum0 + lsum0;
        float zg1 = (R * se) * ssum1 + lsum1;

        float wo0 = u0 * 2.0f - 1.0f;
        float wo1 = r1v * 2.0f - 1.0f;
        bool nonzero = !((wo0 == 0.0f) && (wo1 == 0.0f));
        bool c1 = (fabsf(wo0) > fabsf(wo1)) && nonzero;
        bool c2 = (!c1) && nonzero;
        float sa0 = (wo0 == 0.0f) ? 1.0f : wo0;
        float sa1 = (wo1 == 0.0f) ? 1.0f : wo1;
        float phi = c1 ? (0.78539816339f * wo1 / sa0)
                       : (1.57079632679f - 0.78539816339f * wo0 / sa1);
        float rr = c1 ? wo0 : (c2 ? wo1 : 0.0f);
        float zl0 = rr * cosf(phi);
        float zl1 = rr * sinf(phi);

        float z0 = lambert ? zl0 : zg0;
        float z1 = lambert ? zl1 : zg1;

        float lp[9];
        #pragma unroll
        for (int m = 0; m < 8; ++m) {
            float e0 = (z0 - h[2 * m])     / es0[m];
            float e1 = (z1 - h[2 * m + 1]) / es1[m];
            float wm = wraw[m] / wsum;
            lp[m] = (-1.83787706640934548356f + logf(wm + 1e-5f))
                    - 0.5f * (e0 * e0 + e1 * e1)
                    - (h[16 + 2 * m] + h[16 + 2 * m + 1]);
        }
        float pdf = (z0 * z0 + z1 * z1 > 1.0f) ? 0.0f : 0.31830988618f;
        lp[8] = logf(pdf + 1e-5f) + logf(wL);

        float mx = lp[0];
        #pragma unroll
        for (int j = 1; j < 9; ++j) mx = fmaxf(mx, lp[j]);
        float s = 0.0f;
        #pragma unroll
        for (int j = 0; j < 9; ++j) s += expf(lp[j] - mx);
        float lse = mx + logf(s);

        out[(size_t)row * 2 + 0] = z0;
        out[(size_t)row * 2 + 1] = z1;
        out[(size_t)2 * NTOT + row] = lse;
    }
}

extern "C" void kernel_launch(void* const* d_in, const int* in_sizes, int n_in,
                              void* d_out, int out_size, void* d_ws, size_t ws_size,
                              hipStream_t stream) {
    const float* cond = (const float*)d_in[0];
    const float* rnd  = (const float*)d_in[1];
    const float* W0 = (const float*)d_in[2];  const float* b0 = (const float*)d_in[3];
    const float* W1 = (const float*)d_in[4];  const float* b1 = (const float*)d_in[5];
    const float* W2 = (const float*)d_in[6];  const float* b2 = (const float*)d_in[7];
    const float* W3 = (const float*)d_in[8];  const float* b3 = (const float*)d_in[9];
    const float* W4 = (const float*)d_in[10]; const float* b4 = (const float*)d_in[11];
    float* out = (float*)d_out;

    dim3 grid(NTOT / ROWS);
    dim3 block(THREADS);
    size_t shmem = (size_t)2 * 128 * PITCH * sizeof(float);
    hipLaunchKernelGGL(gmm_fused, grid, block, shmem, stream,
                       cond, rnd, W0, b0, W1, b1, W2, b2, W3, b3, W4, b4, out);
}

// Round 2
// 996.529 us; speedup vs baseline: 1.2105x; 1.2105x over previous
//
#include <hip/hip_runtime.h>
#include <math.h>

#define NTOT   262144
#define ROWS   64
#define THREADS 512
#define KB     16

__global__ __launch_bounds__(THREADS, 4)
void gmm_fused(const float* __restrict__ cond,
               const float* __restrict__ rnd,
               const float* __restrict__ W0, const float* __restrict__ b0,
               const float* __restrict__ W1, const float* __restrict__ b1,
               const float* __restrict__ W2, const float* __restrict__ b2,
               const float* __restrict__ W3, const float* __restrict__ b3,
               const float* __restrict__ W4, const float* __restrict__ b4,
               float* __restrict__ out)
{
    extern __shared__ float smem[];
    float* Bs0 = smem;               // [128][64]
    float* Bs1 = smem + 128 * 64;    // [128][64]

    const int tid  = threadIdx.x;
    const int lane = tid & 63;
    const int wv   = tid >> 6;
    const int row0 = blockIdx.x * ROWS;

    // ---- stage cond^T into Bs0[c][r]: lane==r -> stride-1 writes, conflict-free ----
    {
        const float4* cond4 = (const float4*)cond;
        #pragma unroll
        for (int p = 0; p < 2; ++p) {
            int i  = p * THREADS + tid;      // 0..1023
            int r  = i & 63;
            int c4 = i >> 6;                 // 0..15
            float4 v = cond4[(size_t)(row0 + r) * 16 + c4];
            Bs0[(4 * c4 + 0) * 64 + r] = v.x;
            Bs0[(4 * c4 + 1) * 64 + r] = v.y;
            Bs0[(4 * c4 + 2) * 64 + r] = v.z;
            Bs0[(4 * c4 + 3) * 64 + r] = v.w;
        }
    }
    __syncthreads();

    const int wc16 = __builtin_amdgcn_readfirstlane(wv * 16);

    // ---- L0: 64 -> 128 (relu): Bs0 -> Bs1 ----
    {
        float acc[16];
        #pragma unroll
        for (int c = 0; c < 16; ++c) acc[c] = b0[wc16 + c];
        for (int kb = 0; kb < 64; kb += KB) {
            float a[KB];
            #pragma unroll
            for (int kk = 0; kk < KB; ++kk) a[kk] = Bs0[(kb + kk) * 64 + lane];
            #pragma unroll
            for (int kk = 0; kk < KB; ++kk) {
                const float* wr = W0 + (kb + kk) * 128 + wc16;
                #pragma unroll
                for (int c = 0; c < 16; ++c) acc[c] = fmaf(a[kk], wr[c], acc[c]);
            }
        }
        #pragma unroll
        for (int c = 0; c < 16; ++c)
            Bs1[(wc16 + c) * 64 + lane] = fmaxf(acc[c], 0.0f);
    }
    __syncthreads();

    // ---- L1 (128->512, relu) + L2 (512->128) fused over 4 chunks of 128 ----
    float acc2[16];
    #pragma unroll
    for (int c = 0; c < 16; ++c) acc2[c] = b2[wc16 + c];

    for (int chunk = 0; chunk < 4; ++chunk) {
        float t[16];
        const int cb = chunk * 128 + wc16;
        #pragma unroll
        for (int c = 0; c < 16; ++c) t[c] = b1[cb + c];

        for (int kb = 0; kb < 128; kb += KB) {
            float a[KB];
            #pragma unroll
            for (int kk = 0; kk < KB; ++kk) a[kk] = Bs1[(kb + kk) * 64 + lane];
            #pragma unroll
            for (int kk = 0; kk < KB; ++kk) {
                const float* wr = W1 + (size_t)(kb + kk) * 512 + cb;
                #pragma unroll
                for (int c = 0; c < 16; ++c) t[c] = fmaf(a[kk], wr[c], t[c]);
            }
        }
        __syncthreads();   // everyone done reading Bs0 (L0 input / prev chunk)
        #pragma unroll
        for (int c = 0; c < 16; ++c)
            Bs0[(wc16 + c) * 64 + lane] = fmaxf(t[c], 0.0f);
        __syncthreads();   // chunk activations visible

        for (int kb = 0; kb < 128; kb += KB) {
            float a[KB];
            #pragma unroll
            for (int kk = 0; kk < KB; ++kk) a[kk] = Bs0[(kb + kk) * 64 + lane];
            #pragma unroll
            for (int kk = 0; kk < KB; ++kk) {
                const float* wr = W2 + (size_t)(chunk * 128 + kb + kk) * 128 + wc16;
                #pragma unroll
                for (int c = 0; c < 16; ++c) acc2[c] = fmaf(a[kk], wr[c], acc2[c]);
            }
        }
    }
    // all waves have passed chunk-3's first barrier => all Bs1 (h1) reads done
    #pragma unroll
    for (int c = 0; c < 16; ++c)
        Bs1[(wc16 + c) * 64 + lane] = fmaxf(acc2[c], 0.0f);
    __syncthreads();

    // ---- L3: 128 -> 32 (relu): Bs1 -> Bs0, 4 cols/wave ----
    const int wc4 = __builtin_amdgcn_readfirstlane(wv * 4);
    {
        float acc[4];
        #pragma unroll
        for (int c = 0; c < 4; ++c) acc[c] = b3[wc4 + c];
        for (int kb = 0; kb < 128; kb += KB) {
            float a[KB];
            #pragma unroll
            for (int kk = 0; kk < KB; ++kk) a[kk] = Bs1[(kb + kk) * 64 + lane];
            #pragma unroll
            for (int kk = 0; kk < KB; ++kk) {
                const float* wr = W3 + (kb + kk) * 32 + wc4;
                #pragma unroll
                for (int c = 0; c < 4; ++c) acc[c] = fmaf(a[kk], wr[c], acc[c]);
            }
        }
        #pragma unroll
        for (int c = 0; c < 4; ++c)
            Bs0[(wc4 + c) * 64 + lane] = fmaxf(acc[c], 0.0f);
    }
    __syncthreads();

    // ---- L4: 32 -> 41 (no relu): Bs0 -> Bs1, 6 cols/wave (guarded) ----
    const int wc6 = __builtin_amdgcn_readfirstlane(wv * 6);
    {
        float acc[6];
        #pragma unroll
        for (int c = 0; c < 6; ++c) acc[c] = (wc6 + c < 41) ? b4[wc6 + c] : 0.0f;
        {
            float a[32];
            #pragma unroll
            for (int kk = 0; kk < 32; ++kk) a[kk] = Bs0[kk * 64 + lane];
            #pragma unroll
            for (int kk = 0; kk < 32; ++kk) {
                const float* wr = W4 + kk * 41;
                #pragma unroll
                for (int c = 0; c < 6; ++c)
                    if (wc6 + c < 41) acc[c] = fmaf(a[kk], wr[wc6 + c], acc[c]);
            }
        }
        #pragma unroll
        for (int c = 0; c < 6; ++c)
            if (wc6 + c < 41) Bs1[(wc6 + c) * 64 + lane] = acc[c];
    }
    __syncthreads();

    // ---- epilogue: wave 0, one lane per row ----
    if (wv == 0) {
        const int row = row0 + lane;
        float h[41];
        #pragma unroll
        for (int j = 0; j < 41; ++j) h[j] = Bs1[j * 64 + lane];

        float2 rv = ((const float2*)rnd)[row];
        float r0v = rv.x, r1v = rv.y;

        float wraw[9];
        float wsum = 0.0f;
        #pragma unroll
        for (int j = 0; j < 9; ++j) { wraw[j] = fabsf(h[32 + j]); wsum += wraw[j]; }
        float wL = wraw[8] / wsum;

        const bool lambert = r0v < wL;
        float u0 = lambert ? (r0v / wL) : ((r0v - wL) / (1.0f - wL));
        float U1 = lambert ? 0.5f : u0;
        U1 = fmaxf(U1, 1e-12f);
        float R  = sqrtf(-2.0f * logf(U1));
        float th = 6.28318530717958647692f * r1v;
        float ce = cosf(th), se = sinf(th);

        float es0[8], es1[8];
        float ssum0 = 0.0f, ssum1 = 0.0f, lsum0 = 0.0f, lsum1 = 0.0f;
        #pragma unroll
        for (int m = 0; m < 8; ++m) {
            es0[m] = expf(h[16 + 2 * m]);
            es1[m] = expf(h[16 + 2 * m + 1]);
            ssum0 += es0[m]; ssum1 += es1[m];
            lsum0 += h[2 * m]; lsum1 += h[2 * m + 1];
        }
        float zg0 = (R * ce) * ssum0 + lsum0;
        float zg1 = (R * se) * ssum1 + lsum1;

        float wo0 = u0 * 2.0f - 1.0f;
        float wo1 = r1v * 2.0f - 1.0f;
        bool nonzero = !((wo0 == 0.0f) && (wo1 == 0.0f));
        bool c1 = (fabsf(wo0) > fabsf(wo1)) && nonzero;
        bool c2 = (!c1) && nonzero;
        float sa0 = (wo0 == 0.0f) ? 1.0f : wo0;
        float sa1 = (wo1 == 0.0f) ? 1.0f : wo1;
        float phi = c1 ? (0.78539816339f * wo1 / sa0)
                       : (1.57079632679f - 0.78539816339f * wo0 / sa1);
        float rr = c1 ? wo0 : (c2 ? wo1 : 0.0f);
        float zl0 = rr * cosf(phi);
        float zl1 = rr * sinf(phi);

        float z0 = lambert ? zl0 : zg0;
        float z1 = lambert ? zl1 : zg1;

        float lp[9];
        #pragma unroll
        for (int m = 0; m < 8; ++m) {
            float e0 = (z0 - h[2 * m])     / es0[m];
            float e1 = (z1 - h[2 * m + 1]) / es1[m];
            float wm = wraw[m] / wsum;
            lp[m] = (-1.83787706640934548356f + logf(wm + 1e-5f))
                    - 0.5f * (e0 * e0 + e1 * e1)
                    - (h[16 + 2 * m] + h[16 + 2 * m + 1]);
        }
        float pdf = (z0 * z0 + z1 * z1 > 1.0f) ? 0.0f : 0.31830988618f;
        lp[8] = logf(pdf + 1e-5f) + logf(wL);

        float mx = lp[0];
        #pragma unroll
        for (int j = 1; j < 9; ++j) mx = fmaxf(mx, lp[j]);
        float s = 0.0f;
        #pragma unroll
        for (int j = 0; j < 9; ++j) s += expf(lp[j] - mx);
        float lse = mx + logf(s);

        ((float2*)out)[row] = make_float2(z0, z1);
        out[(size_t)2 * NTOT + row] = lse;
    }
}

extern "C" void kernel_launch(void* const* d_in, const int* in_sizes, int n_in,
                              void* d_out, int out_size, void* d_ws, size_t ws_size,
                              hipStream_t stream) {
    const float* cond = (const float*)d_in[0];
    const float* rnd  = (const float*)d_in[1];
    const float* W0 = (const float*)d_in[2];  const float* b0 = (const float*)d_in[3];
    const float* W1 = (const float*)d_in[4];  const float* b1 = (const float*)d_in[5];
    const float* W2 = (const float*)d_in[6];  const float* b2 = (const float*)d_in[7];
    const float* W3 = (const float*)d_in[8];  const float* b3 = (const float*)d_in[9];
    const float* W4 = (const float*)d_in[10]; const float* b4 = (const float*)d_in[11];
    float* out = (float*)d_out;

    dim3 grid(NTOT / ROWS);
    dim3 block(THREADS);
    size_t shmem = (size_t)2 * 128 * 64 * sizeof(float);
    hipLaunchKernelGGL(gmm_fused, grid, block, shmem, stream,
                       cond, rnd, W0, b0, W1, b1, W2, b2, W3, b3, W4, b4, out);
}

// Round 3
// 984.283 us; speedup vs baseline: 1.2256x; 1.0124x over previous
//
#include <hip/hip_runtime.h>
#include <math.h>

#define NTOT    262144
#define ROWS    128
#define THREADS 512
#define KB      8

__global__ __launch_bounds__(THREADS, 4)
void gmm_fused(const float* __restrict__ cond,
               const float* __restrict__ rnd,
               const float* __restrict__ W0, const float* __restrict__ b0,
               const float* __restrict__ W1, const float* __restrict__ b1,
               const float* __restrict__ W2, const float* __restrict__ b2,
               const float* __restrict__ W3, const float* __restrict__ b3,
               const float* __restrict__ W4, const float* __restrict__ b4,
               float* __restrict__ out)
{
    extern __shared__ float smem[];
    float* BsA = smem;               // [128][128]  wide activation buffer (64 KB)
    float* BsC = smem + 128 * 128;   // [32][128]   chunk buffer (16 KB)

    const int tid  = threadIdx.x;
    const int lane = tid & 63;
    const int wv   = tid >> 6;
    const int row0 = blockIdx.x * ROWS;
    const int r2   = 2 * lane;       // this lane's row pair within the block

    // ---- stage cond^T into BsA[c][r], c=0..63 ----
    {
        const float4* cond4 = (const float4*)cond;
        #pragma unroll
        for (int p = 0; p < 4; ++p) {
            int i  = p * THREADS + tid;     // 0..2047
            int r  = i & 127;
            int c4 = i >> 7;                // 0..15
            float4 v = cond4[(size_t)(row0 + r) * 16 + c4];
            BsA[(4 * c4 + 0) * 128 + r] = v.x;
            BsA[(4 * c4 + 1) * 128 + r] = v.y;
            BsA[(4 * c4 + 2) * 128 + r] = v.z;
            BsA[(4 * c4 + 3) * 128 + r] = v.w;
        }
    }
    __syncthreads();

    const int wc16 = __builtin_amdgcn_readfirstlane(wv * 16);
    const int wc4  = __builtin_amdgcn_readfirstlane(wv * 4);
    const int wc6  = __builtin_amdgcn_readfirstlane(wv * 6);

    // ---- L0: 64 -> 128 (relu), 16 cols/wave x 2 rows/lane ----
    {
        float acc0[16], acc1[16];
        #pragma unroll
        for (int c = 0; c < 16; ++c) { acc0[c] = b0[wc16 + c]; acc1[c] = acc0[c]; }
        for (int kb = 0; kb < 64; kb += KB) {
            float2 a[KB];
            #pragma unroll
            for (int kk = 0; kk < KB; ++kk)
                a[kk] = *(const float2*)&BsA[(kb + kk) * 128 + r2];
            #pragma unroll
            for (int kk = 0; kk < KB; ++kk) {
                const float* wr = W0 + (kb + kk) * 128 + wc16;
                #pragma unroll
                for (int c = 0; c < 16; ++c) {
                    float w = wr[c];
                    acc0[c] = fmaf(a[kk].x, w, acc0[c]);
                    acc1[c] = fmaf(a[kk].y, w, acc1[c]);
                }
            }
        }
        __syncthreads();   // all BsA (cond) reads done
        #pragma unroll
        for (int c = 0; c < 16; ++c)
            *(float2*)&BsA[(wc16 + c) * 128 + r2] =
                make_float2(fmaxf(acc0[c], 0.0f), fmaxf(acc1[c], 0.0f));
    }
    __syncthreads();

    // ---- L1 (128->512 relu) + L2 (512->128) fused over 16 chunks of 32 cols ----
    float acc20[16], acc21[16];
    #pragma unroll
    for (int c = 0; c < 16; ++c) { acc20[c] = b2[wc16 + c]; acc21[c] = acc20[c]; }

    for (int chunk = 0; chunk < 16; ++chunk) {
        const int cb = chunk * 32 + wc4;
        float t0[4], t1[4];
        #pragma unroll
        for (int c = 0; c < 4; ++c) { t0[c] = b1[cb + c]; t1[c] = t0[c]; }

        for (int kb = 0; kb < 128; kb += KB) {
            float2 a[KB];
            #pragma unroll
            for (int kk = 0; kk < KB; ++kk)
                a[kk] = *(const float2*)&BsA[(kb + kk) * 128 + r2];
            #pragma unroll
            for (int kk = 0; kk < KB; ++kk) {
                const float* wr = W1 + (size_t)(kb + kk) * 512 + cb;
                #pragma unroll
                for (int c = 0; c < 4; ++c) {
                    float w = wr[c];
                    t0[c] = fmaf(a[kk].x, w, t0[c]);
                    t1[c] = fmaf(a[kk].y, w, t1[c]);
                }
            }
        }
        __syncthreads();   // prev chunk's BsC reads complete
        #pragma unroll
        for (int c = 0; c < 4; ++c)
            *(float2*)&BsC[(wc4 + c) * 128 + r2] =
                make_float2(fmaxf(t0[c], 0.0f), fmaxf(t1[c], 0.0f));
        __syncthreads();   // chunk acts visible

        for (int kb = 0; kb < 32; kb += KB) {
            float2 a[KB];
            #pragma unroll
            for (int kk = 0; kk < KB; ++kk)
                a[kk] = *(const float2*)&BsC[(kb + kk) * 128 + r2];
            #pragma unroll
            for (int kk = 0; kk < KB; ++kk) {
                const float* wr = W2 + (size_t)(chunk * 32 + kb + kk) * 128 + wc16;
                #pragma unroll
                for (int c = 0; c < 16; ++c) {
                    float w = wr[c];
                    acc20[c] = fmaf(a[kk].x, w, acc20[c]);
                    acc21[c] = fmaf(a[kk].y, w, acc21[c]);
                }
            }
        }
    }
    // after chunk15's first barrier no wave reads BsA again -> safe to overwrite
    #pragma unroll
    for (int c = 0; c < 16; ++c)
        *(float2*)&BsA[(wc16 + c) * 128 + r2] =
            make_float2(fmaxf(acc20[c], 0.0f), fmaxf(acc21[c], 0.0f));
    __syncthreads();       // h2 visible; also: all BsC reads done

    // ---- L3: 128 -> 32 (relu), 4 cols/wave ----
    {
        float a30[4], a31[4];
        #pragma unroll
        for (int c = 0; c < 4; ++c) { a30[c] = b3[wc4 + c]; a31[c] = a30[c]; }
        for (int kb = 0; kb < 128; kb += KB) {
            float2 a[KB];
            #pragma unroll
            for (int kk = 0; kk < KB; ++kk)
                a[kk] = *(const float2*)&BsA[(kb + kk) * 128 + r2];
            #pragma unroll
            for (int kk = 0; kk < KB; ++kk) {
                const float* wr = W3 + (kb + kk) * 32 + wc4;
                #pragma unroll
                for (int c = 0; c < 4; ++c) {
                    float w = wr[c];
                    a30[c] = fmaf(a[kk].x, w, a30[c]);
                    a31[c] = fmaf(a[kk].y, w, a31[c]);
                }
            }
        }
        #pragma unroll
        for (int c = 0; c < 4; ++c)
            *(float2*)&BsC[(wc4 + c) * 128 + r2] =
                make_float2(fmaxf(a30[c], 0.0f), fmaxf(a31[c], 0.0f));
    }
    __syncthreads();       // BsC (h3) visible; all BsA (h2) reads done

    // ---- L4: 32 -> 41 (no relu), 6 cols/wave guarded ----
    {
        float a40[6], a41[6];
        #pragma unroll
        for (int c = 0; c < 6; ++c) {
            float b = (wc6 + c < 41) ? b4[wc6 + c] : 0.0f;
            a40[c] = b; a41[c] = b;
        }
        for (int kb = 0; kb < 32; kb += KB) {
            float2 a[KB];
            #pragma unroll
            for (int kk = 0; kk < KB; ++kk)
                a[kk] = *(const float2*)&BsC[(kb + kk) * 128 + r2];
            #pragma unroll
            for (int kk = 0; kk < KB; ++kk) {
                const float* wr = W4 + (kb + kk) * 41;
                #pragma unroll
                for (int c = 0; c < 6; ++c)
                    if (wc6 + c < 41) {
                        float w = wr[wc6 + c];
                        a40[c] = fmaf(a[kk].x, w, a40[c]);
                        a41[c] = fmaf(a[kk].y, w, a41[c]);
                    }
            }
        }
        #pragma unroll
        for (int c = 0; c < 6; ++c)
            if (wc6 + c < 41)
                *(float2*)&BsA[(wc6 + c) * 128 + r2] = make_float2(a40[c], a41[c]);
    }
    __syncthreads();

    // ---- epilogue: first 2 waves, one lane per row ----
    if (tid < 128) {
        const int e   = tid;
        const int row = row0 + e;
        float h[41];
        #pragma unroll
        for (int j = 0; j < 41; ++j) h[j] = BsA[j * 128 + e];

        float2 rv = ((const float2*)rnd)[row];
        float r0v = rv.x, r1v = rv.y;

        float wraw[9];
        float wsum = 0.0f;
        #pragma unroll
        for (int j = 0; j < 9; ++j) { wraw[j] = fabsf(h[32 + j]); wsum += wraw[j]; }
        float wL = wraw[8] / wsum;

        const bool lambert = r0v < wL;
        float u0 = lambert ? (r0v / wL) : ((r0v - wL) / (1.0f - wL));
        float U1 = lambert ? 0.5f : u0;
        U1 = fmaxf(U1, 1e-12f);
        float R  = sqrtf(-2.0f * logf(U1));
        float th = 6.28318530717958647692f * r1v;
        float ce = cosf(th), se = sinf(th);

        float es0[8], es1[8];
        float ssum0 = 0.0f, ssum1 = 0.0f, lsum0 = 0.0f, lsum1 = 0.0f;
        #pragma unroll
        for (int m = 0; m < 8; ++m) {
            es0[m] = expf(h[16 + 2 * m]);
            es1[m] = expf(h[16 + 2 * m + 1]);
            ssum0 += es0[m]; ssum1 += es1[m];
            lsum0 += h[2 * m]; lsum1 += h[2 * m + 1];
        }
        float zg0 = (R * ce) * ssum0 + lsum0;
        float zg1 = (R * se) * ssum1 + lsum1;

        float wo0 = u0 * 2.0f - 1.0f;
        float wo1 = r1v * 2.0f - 1.0f;
        bool nonzero = !((wo0 == 0.0f) && (wo1 == 0.0f));
        bool c1 = (fabsf(wo0) > fabsf(wo1)) && nonzero;
        bool c2 = (!c1) && nonzero;
        float sa0 = (wo0 == 0.0f) ? 1.0f : wo0;
        float sa1 = (wo1 == 0.0f) ? 1.0f : wo1;
        float phi = c1 ? (0.78539816339f * wo1 / sa0)
                       : (1.57079632679f - 0.78539816339f * wo0 / sa1);
        float rr = c1 ? wo0 : (c2 ? wo1 : 0.0f);
        float zl0 = rr * cosf(phi);
        float zl1 = rr * sinf(phi);

        float z0 = lambert ? zl0 : zg0;
        float z1 = lambert ? zl1 : zg1;

        float lp[9];
        #pragma unroll
        for (int m = 0; m < 8; ++m) {
            float e0 = (z0 - h[2 * m])     / es0[m];
            float e1 = (z1 - h[2 * m + 1]) / es1[m];
            float wm = wraw[m] / wsum;
            lp[m] = (-1.83787706640934548356f + logf(wm + 1e-5f))
                    - 0.5f * (e0 * e0 + e1 * e1)
                    - (h[16 + 2 * m] + h[16 + 2 * m + 1]);
        }
        float pdf = (z0 * z0 + z1 * z1 > 1.0f) ? 0.0f : 0.31830988618f;
        lp[8] = logf(pdf + 1e-5f) + logf(wL);

        float mx = lp[0];
        #pragma unroll
        for (int j = 1; j < 9; ++j) mx = fmaxf(mx, lp[j]);
        float s = 0.0f;
        #pragma unroll
        for (int j = 0; j < 9; ++j) s += expf(lp[j] - mx);
        float lse = mx + logf(s);

        ((float2*)out)[row] = make_float2(z0, z1);
        out[(size_t)2 * NTOT + row] = lse;
    }
}

extern "C" void kernel_launch(void* const* d_in, const int* in_sizes, int n_in,
                              void* d_out, int out_size, void* d_ws, size_t ws_size,
                              hipStream_t stream) {
    const float* cond = (const float*)d_in[0];
    const float* rnd  = (const float*)d_in[1];
    const float* W0 = (const float*)d_in[2];  const float* b0 = (const float*)d_in[3];
    const float* W1 = (const float*)d_in[4];  const float* b1 = (const float*)d_in[5];
    const float* W2 = (const float*)d_in[6];  const float* b2 = (const float*)d_in[7];
    const float* W3 = (const float*)d_in[8];  const float* b3 = (const float*)d_in[9];
    const float* W4 = (const float*)d_in[10]; const float* b4 = (const float*)d_in[11];
    float* out = (float*)d_out;

    dim3 grid(NTOT / ROWS);
    dim3 block(THREADS);
    size_t shmem = (size_t)(128 * 128 + 32 * 128) * sizeof(float);  // 80 KB
    hipLaunchKernelGGL(gmm_fused, grid, block, shmem, stream,
                       cond, rnd, W0, b0, W1, b1, W2, b2, W3, b3, W4, b4, out);
}